// Round 4
// baseline (264.166 us; speedup 1.0000x reference)
//
#include <hip/hip_runtime.h>

// LSTM B=4096, S=512, INPUT=1, HIDDEN=20 + linear head.
// R4: 2 groups x 2 chains-per-lane (ILP-2). 4 chains per 64-lane wave,
// 1024 waves = 1/SIMD, evenly spread (4 blocks/CU). Each lane = unit j of
// TWO chains: weights stored once (40 VGPRs, shared), two independent
// recurrences interleave to self-hide trans/LDS latency at 1 wave/SIMD.
// Trans reduced 10 -> 7 per chain-step by rcp fusion:
//   c' = f*c + i*g = [c*B*G + A*(2-G)] / (A*B*G),  A=1+e_f,B=1+e_i,G=1+e_g
//   h  = o*tanh(c') = (2-C)/(O*C),                 O=1+e_o,C=1+e_c
// (e = exp2 of pre-scaled gate accumulator; 5 exp2 + 2 rcp per chain-step).
// Idle lanes (j>=20) clamp to unit 0 -> identical value to same address:
// benign duplicate LDS write, no exec-mask branches in the hot loop.
// h rings: 4 regions (chain 0..3) of 16 rows x 12 words, region stride 200
// words (mod 32 = {0,8,16,24}: broadcast reads 2-addr per instr = free).

#define BATCH 4096
#define SLEN  512
#define H     20
#define CHUNK 16
#define LOG2E 1.44269504088896340736f
#define REG   200   // words per ring region (16*12=192 used + 8 pad)
#define RS    12    // words per h row (10 half2 used + 2 pad)

typedef _Float16 h2 __attribute__((ext_vector_type(2)));

__device__ __forceinline__ float fexp2(float x) { return __builtin_amdgcn_exp2f(x); }
__device__ __forceinline__ float frcp(float x)  { return __builtin_amdgcn_rcpf(x); }
__device__ __forceinline__ h2 bch2(unsigned int u) { return __builtin_bit_cast(h2, u); }

__global__ __launch_bounds__(64, 1) void lstm_fused(
    const float* __restrict__ x,      // [B, S, 1]
    const float* __restrict__ W_ih,   // [80, 1]
    const float* __restrict__ W_hh,   // [80, 20]
    const float* __restrict__ b_ih,   // [80]
    const float* __restrict__ b_hh,   // [80]
    const float* __restrict__ W_lin,  // [1, 20]
    const float* __restrict__ b_lin,  // [1]
    float* __restrict__ out)          // [B, S, 1]
{
    __shared__ __align__(16) unsigned int hw[4 * REG];  // 4 chain ring regions
    __shared__ float xls[4][CHUNK];

    const int lane = threadIdx.x;       // 0..63
    const int g    = lane >> 5;         // group 0/1 (lanes 0-31 / 32-63)
    const int j    = lane & 31;         // 0..19 valid units
    const int ju   = (j < H) ? j : 0;   // clamp: idle lanes mirror unit 0
    const long base = (long)blockIdx.x * 4;  // 4 chains per block, exact

    const float s1 = -LOG2E;            // sigmoid pre-scale
    const float s2 = -2.0f * LOG2E;     // tanh pre-scale

    // ---- per-lane weights: 4 gate rows x 10 half2 (40 VGPRs), pre-scaled,
    //      SHARED by both chains ----
    h2 w2[4][10];
    float bb[4], xw[4];
#pragma unroll
    for (int gg = 0; gg < 4; ++gg) {
        const int row = gg * H + ju;
        const float sc = (gg == 2) ? s2 : s1;   // torch gate order i,f,g,o
#pragma unroll
        for (int k = 0; k < 10; ++k) {
            h2 t;
            t.x = (_Float16)(sc * W_hh[row * H + 2 * k]);
            t.y = (_Float16)(sc * W_hh[row * H + 2 * k + 1]);
            w2[gg][k] = t;
        }
        bb[gg] = sc * (b_ih[row] + b_hh[row]);
        xw[gg] = sc * W_ih[row];
    }
    h2 wl2[10];
#pragma unroll
    for (int k = 0; k < 10; ++k) {
        h2 t;
        t.x = (_Float16)W_lin[2 * k];
        t.y = (_Float16)W_lin[2 * k + 1];
        wl2[k] = t;
    }
    const float blin = b_lin[0];

    // region base for this group's chain pair (chains 2g, 2g+1)
    const unsigned int* grd = hw + g * 2 * REG;
    _Float16*           gwr = (_Float16*)hw + g * 2 * REG * 2;

    // h(-1) = 0 in ring row CHUNK-1 of both chain regions
    gwr[2 * ((CHUNK - 1) * RS) + ju]       = (_Float16)0.0f;
    gwr[2 * (REG + (CHUNK - 1) * RS) + ju] = (_Float16)0.0f;
    float c0 = 0.0f, c1 = 0.0f;

    const int  qx = lane >> 4;      // x/head: lane -> (chain qx, step sx)
    const int  sx = lane & 15;
    const float* xq = x   + (base + qx) * SLEN;
    float*       oq = out + (base + qx) * SLEN;

#pragma unroll 1
    for (int T = 0; T < SLEN; T += CHUNK) {
        xls[qx][sx] = xq[T + sx];   // stage x chunk for all 4 chains

#pragma unroll
        for (int i = 0; i < CHUNK; ++i) {
            const int ro = ((i + CHUNK - 1) & (CHUNK - 1)) * RS;
            // h(t-1) rows for both chains: 20 fp16 = b128+b128+b64 each
            const uint4 A0 = *(const uint4*)(grd + ro);
            const uint4 B0 = *(const uint4*)(grd + ro + 4);
            const uint2 C0 = *(const uint2*)(grd + ro + 8);
            const uint4 A1 = *(const uint4*)(grd + REG + ro);
            const uint4 B1 = *(const uint4*)(grd + REG + ro + 4);
            const uint2 C1 = *(const uint2*)(grd + REG + ro + 8);
            const unsigned int pw0[10] = {A0.x, A0.y, A0.z, A0.w,
                                          B0.x, B0.y, B0.z, B0.w, C0.x, C0.y};
            const unsigned int pw1[10] = {A1.x, A1.y, A1.z, A1.w,
                                          B1.x, B1.y, B1.z, B1.w, C1.x, C1.y};
            const float xt0 = xls[2 * g][i];       // broadcast (2 addrs: free)
            const float xt1 = xls[2 * g + 1][i];

            float a0[4], a1[4];
#pragma unroll
            for (int gg = 0; gg < 4; ++gg) {
                a0[gg] = fmaf(xt0, xw[gg], bb[gg]);
                a1[gg] = fmaf(xt1, xw[gg], bb[gg]);
            }
#pragma unroll
            for (int k = 0; k < 10; ++k) {
#pragma unroll
                for (int gg = 0; gg < 4; ++gg) {
                    a0[gg] = __builtin_amdgcn_fdot2(bch2(pw0[k]), w2[gg][k], a0[gg], false);
                    a1[gg] = __builtin_amdgcn_fdot2(bch2(pw1[k]), w2[gg][k], a1[gg], false);
                }
            }
            // ---- chain 0 activations (rcp-fused) ----
            {
                const float eI = fexp2(a0[0]), eF = fexp2(a0[1]);
                const float eG = fexp2(a0[2]), eO = fexp2(a0[3]);
                const float B = 1.0f + eI, A = 1.0f + eF, G = 1.0f + eG;
                const float P = B * G;
                const float N = fmaf(c0, P, A * (2.0f - G));
                c0 = N * frcp(A * P);
                const float eC = fexp2(s2 * c0);
                const float C = 1.0f + eC;
                const float hv = (2.0f - C) * frcp((1.0f + eO) * C);
                gwr[2 * (i * RS) + ju] = (_Float16)hv;
            }
            // ---- chain 1 activations (independent: interleaves with 0) ----
            {
                const float eI = fexp2(a1[0]), eF = fexp2(a1[1]);
                const float eG = fexp2(a1[2]), eO = fexp2(a1[3]);
                const float B = 1.0f + eI, A = 1.0f + eF, G = 1.0f + eG;
                const float P = B * G;
                const float N = fmaf(c1, P, A * (2.0f - G));
                c1 = N * frcp(A * P);
                const float eC = fexp2(s2 * c1);
                const float C = 1.0f + eC;
                const float hv = (2.0f - C) * frcp((1.0f + eO) * C);
                gwr[2 * (REG + i * RS) + ju] = (_Float16)hv;
            }
        }

        // ---- deferred head: lane -> (chain qx, step sx), all 64 lanes ----
        {
            const unsigned int* rr = hw + qx * REG + sx * RS;
            const uint4 Ah = *(const uint4*)rr;
            const uint4 Bh = *(const uint4*)(rr + 4);
            const uint2 Ch = *(const uint2*)(rr + 8);
            const unsigned int pw[10] = {Ah.x, Ah.y, Ah.z, Ah.w,
                                         Bh.x, Bh.y, Bh.z, Bh.w, Ch.x, Ch.y};
            float y = blin;
#pragma unroll
            for (int k = 0; k < 10; ++k)
                y = __builtin_amdgcn_fdot2(bch2(pw[k]), wl2[k], y, false);
            oq[T + sx] = y;   // 4 coalesced 64B segments
        }
    }
}

extern "C" void kernel_launch(void* const* d_in, const int* in_sizes, int n_in,
                              void* d_out, int out_size, void* d_ws, size_t ws_size,
                              hipStream_t stream) {
    const float* x     = (const float*)d_in[0];
    const float* W_ih  = (const float*)d_in[1];
    const float* W_hh  = (const float*)d_in[2];
    const float* b_ih  = (const float*)d_in[3];
    const float* b_hh  = (const float*)d_in[4];
    const float* W_lin = (const float*)d_in[5];
    const float* b_lin = (const float*)d_in[6];
    float* out = (float*)d_out;

    lstm_fused<<<BATCH / 4, 64, 0, stream>>>(x, W_ih, W_hh, b_ih, b_hh,
                                             W_lin, b_lin, out);
}

// Round 5
// 260.793 us; speedup vs baseline: 1.0129x; 1.0129x over previous
//
#include <hip/hip_runtime.h>

// LSTM B=4096, S=512, INPUT=1, HIDDEN=20 + linear head.
// R5: R3's optimal SIMT packing (3 groups x 20 lanes = 3 chains/wave, lane =
// unit, all 4 gates per lane => 40 dot2 per wave-step per set, ~13.3
// dot2/chain-step vs 12.5 perfect) PLUS a second independent chain-set per
// lane (6 chains/wave total). Both sets share the same 40 weight VGPRs
// (weights are per-unit). The two sets' dep chains (LDS h round-trip ~120cyc,
// exp2->rcp chains) interleave in one instruction stream -> latency hiding
// without needing co-resident waves (683 waves = ~0.67/SIMD).
// Activations rcp-fused (R4 algebra, verified): per chain-step 5 exp2 + 2 rcp.
//   c' = [c*B*G + A*(2-G)] / (A*B*G);  h = (2-C)/(O*C)
// h rings: 6 regions of 16 rows x 12 words, region stride 200 words
// (offsets mod 32 = {0,8,16,24,0,8}: each 3-address broadcast read hits
// disjoint bank quads; overlapping write banks are only 2-way = free).
// Lanes 60..63 mirror lanes 40..43 (same chain/unit/address/value: benign).

#define BATCH 4096
#define SLEN  512
#define H     20
#define CHUNK 16
#define LOG2E 1.44269504088896340736f
#define REG   200   // words per ring region (16*12=192 used + 8 pad)
#define RS    12    // words per h row (10 half2 used + 2 pad)

typedef _Float16 h2 __attribute__((ext_vector_type(2)));

__device__ __forceinline__ float fexp2(float x) { return __builtin_amdgcn_exp2f(x); }
__device__ __forceinline__ float frcp(float x)  { return __builtin_amdgcn_rcpf(x); }
__device__ __forceinline__ h2 bch2(unsigned int u) { return __builtin_bit_cast(h2, u); }

__global__ __launch_bounds__(64, 1) void lstm_fused(
    const float* __restrict__ x,      // [B, S, 1]
    const float* __restrict__ W_ih,   // [80, 1]
    const float* __restrict__ W_hh,   // [80, 20]
    const float* __restrict__ b_ih,   // [80]
    const float* __restrict__ b_hh,   // [80]
    const float* __restrict__ W_lin,  // [1, 20]
    const float* __restrict__ b_lin,  // [1]
    float* __restrict__ out)          // [B, S, 1]
{
    __shared__ __align__(16) unsigned int hw[6 * REG];  // 6 chain ring regions
    __shared__ float xls[6][17];                        // padded: bank spread

    const int lane = threadIdx.x;       // 0..63
    int grp = lane / H;                 // 0..3
    int j   = lane - grp * H;           // unit
    if (grp == 3) { grp = 2; j = lane - 60; }  // lanes 60..63 mirror 40..43

    const int cb  = blockIdx.x * 6;
    const int ch0 = min(cb + grp,     BATCH - 1);   // set-0 chain
    const int ch1 = min(cb + 3 + grp, BATCH - 1);   // set-1 chain
    (void)ch0; (void)ch1;

    const float s1 = -LOG2E;            // sigmoid pre-scale
    const float s2 = -2.0f * LOG2E;     // tanh pre-scale

    // ---- per-lane weights: 4 gate rows x 10 half2 (40 VGPRs), pre-scaled,
    //      shared by both chain-sets ----
    h2 w2[4][10];
    float bb[4], xw[4];
#pragma unroll
    for (int gg = 0; gg < 4; ++gg) {
        const int row = gg * H + j;
        const float sc = (gg == 2) ? s2 : s1;   // torch gate order i,f,g,o
#pragma unroll
        for (int k = 0; k < 10; ++k) {
            h2 t;
            t.x = (_Float16)(sc * W_hh[row * H + 2 * k]);
            t.y = (_Float16)(sc * W_hh[row * H + 2 * k + 1]);
            w2[gg][k] = t;
        }
        bb[gg] = sc * (b_ih[row] + b_hh[row]);
        xw[gg] = sc * W_ih[row];
    }
    h2 wl2[10];
#pragma unroll
    for (int k = 0; k < 10; ++k) {
        h2 t;
        t.x = (_Float16)W_lin[2 * k];
        t.y = (_Float16)W_lin[2 * k + 1];
        wl2[k] = t;
    }
    const float blin = b_lin[0];

    _Float16* hh = (_Float16*)hw;
    const int rb0 = grp * REG;          // set-0 ring base (words)
    const int rb1 = (3 + grp) * REG;    // set-1 ring base

    // h(-1) = 0 in ring row CHUNK-1 of both regions
    hh[2 * (rb0 + (CHUNK - 1) * RS) + j] = (_Float16)0.0f;
    hh[2 * (rb1 + (CHUNK - 1) * RS) + j] = (_Float16)0.0f;
    float c0 = 0.0f, c1 = 0.0f;

    // x-stage / head mapping: round A lane -> (chain qx, step sx), all lanes;
    // round B lanes 0..31 -> chains 4..5.
    const int qx = lane >> 4;
    const int sx = lane & 15;
    const float* xqa = x   + (long)min(cb + qx, BATCH - 1) * SLEN;
    float*       oqa = out + (long)min(cb + qx, BATCH - 1) * SLEN;
    const float* xqb = x   + (long)min(cb + 4 + (qx & 1), BATCH - 1) * SLEN;
    float*       oqb = out + (long)min(cb + 4 + (qx & 1), BATCH - 1) * SLEN;

#pragma unroll 1
    for (int T = 0; T < SLEN; T += CHUNK) {
        xls[qx][sx] = xqa[T + sx];                    // chains 0..3
        if (lane < 32) xls[4 + qx][sx] = xqb[T + sx]; // chains 4..5

#pragma unroll
        for (int i = 0; i < CHUNK; ++i) {
            const int ro = ((i + CHUNK - 1) & (CHUNK - 1)) * RS;
            // h(t-1) rows for both sets: 20 fp16 = b128+b128+b64 each
            const uint4 A0 = *(const uint4*)(hw + rb0 + ro);
            const uint4 B0 = *(const uint4*)(hw + rb0 + ro + 4);
            const uint2 C0 = *(const uint2*)(hw + rb0 + ro + 8);
            const uint4 A1 = *(const uint4*)(hw + rb1 + ro);
            const uint4 B1 = *(const uint4*)(hw + rb1 + ro + 4);
            const uint2 C1 = *(const uint2*)(hw + rb1 + ro + 8);
            const unsigned int pw0[10] = {A0.x, A0.y, A0.z, A0.w,
                                          B0.x, B0.y, B0.z, B0.w, C0.x, C0.y};
            const unsigned int pw1[10] = {A1.x, A1.y, A1.z, A1.w,
                                          B1.x, B1.y, B1.z, B1.w, C1.x, C1.y};
            const float xt0 = xls[grp][i];       // group broadcast
            const float xt1 = xls[3 + grp][i];

            float a0[4], a1[4];
#pragma unroll
            for (int gg = 0; gg < 4; ++gg) {
                a0[gg] = fmaf(xt0, xw[gg], bb[gg]);
                a1[gg] = fmaf(xt1, xw[gg], bb[gg]);
            }
#pragma unroll
            for (int k = 0; k < 10; ++k) {
#pragma unroll
                for (int gg = 0; gg < 4; ++gg) {   // 8 independent dot chains
                    a0[gg] = __builtin_amdgcn_fdot2(bch2(pw0[k]), w2[gg][k], a0[gg], false);
                    a1[gg] = __builtin_amdgcn_fdot2(bch2(pw1[k]), w2[gg][k], a1[gg], false);
                }
            }
            // ---- set-0 activations (rcp-fused) ----
            {
                const float eI = fexp2(a0[0]), eF = fexp2(a0[1]);
                const float eG = fexp2(a0[2]), eO = fexp2(a0[3]);
                const float B = 1.0f + eI, A = 1.0f + eF, G = 1.0f + eG;
                const float P = B * G;
                const float N = fmaf(c0, P, A * (2.0f - G));
                c0 = N * frcp(A * P);
                const float eC = fexp2(s2 * c0);
                const float C = 1.0f + eC;
                const float hv = (2.0f - C) * frcp((1.0f + eO) * C);
                hh[2 * (rb0 + i * RS) + j] = (_Float16)hv;
            }
            // ---- set-1 activations (independent: interleaves with set-0) ----
            {
                const float eI = fexp2(a1[0]), eF = fexp2(a1[1]);
                const float eG = fexp2(a1[2]), eO = fexp2(a1[3]);
                const float B = 1.0f + eI, A = 1.0f + eF, G = 1.0f + eG;
                const float P = B * G;
                const float N = fmaf(c1, P, A * (2.0f - G));
                c1 = N * frcp(A * P);
                const float eC = fexp2(s2 * c1);
                const float C = 1.0f + eC;
                const float hv = (2.0f - C) * frcp((1.0f + eO) * C);
                hh[2 * (rb1 + i * RS) + j] = (_Float16)hv;
            }
        }

        // ---- deferred head, round A: all lanes, chains 0..3 ----
        {
            const unsigned int* rr = hw + qx * REG + sx * RS;
            const uint4 Ah = *(const uint4*)rr;
            const uint4 Bh = *(const uint4*)(rr + 4);
            const uint2 Ch = *(const uint2*)(rr + 8);
            const unsigned int pw[10] = {Ah.x, Ah.y, Ah.z, Ah.w,
                                         Bh.x, Bh.y, Bh.z, Bh.w, Ch.x, Ch.y};
            float y = blin;
#pragma unroll
            for (int k = 0; k < 10; ++k)
                y = __builtin_amdgcn_fdot2(bch2(pw[k]), wl2[k], y, false);
            oqa[T + sx] = y;
        }
        // ---- round B: lanes 0..31, chains 4..5 ----
        if (lane < 32) {
            const unsigned int* rr = hw + (4 + (qx & 1)) * REG + sx * RS;
            const uint4 Ah = *(const uint4*)rr;
            const uint4 Bh = *(const uint4*)(rr + 4);
            const uint2 Ch = *(const uint2*)(rr + 8);
            const unsigned int pw[10] = {Ah.x, Ah.y, Ah.z, Ah.w,
                                         Bh.x, Bh.y, Bh.z, Bh.w, Ch.x, Ch.y};
            float y = blin;
#pragma unroll
            for (int k = 0; k < 10; ++k)
                y = __builtin_amdgcn_fdot2(bch2(pw[k]), wl2[k], y, false);
            oqb[T + sx] = y;
        }
    }
}

extern "C" void kernel_launch(void* const* d_in, const int* in_sizes, int n_in,
                              void* d_out, int out_size, void* d_ws, size_t ws_size,
                              hipStream_t stream) {
    const float* x     = (const float*)d_in[0];
    const float* W_ih  = (const float*)d_in[1];
    const float* W_hh  = (const float*)d_in[2];
    const float* b_ih  = (const float*)d_in[3];
    const float* b_hh  = (const float*)d_in[4];
    const float* W_lin = (const float*)d_in[5];
    const float* b_lin = (const float*)d_in[6];
    float* out = (float*)d_out;

    const int nblocks = (BATCH + 5) / 6;  // 6 chains per 64-lane wave
    lstm_fused<<<nblocks, 64, 0, stream>>>(x, W_ih, W_hh, b_ih, b_hh,
                                           W_lin, b_lin, out);
}